// Round 6
// baseline (533.572 us; speedup 1.0000x reference)
//
#include <hip/hip_runtime.h>

#define VOCAB 21
#define EMB 128
#define H1 64
#define H2 100
#define T1 500
#define TP 100
#define NB 1024
#define LOG2E 1.44269504f

typedef __attribute__((ext_vector_type(8))) short bf16x8;
typedef __attribute__((ext_vector_type(4))) float f32x4;

__device__ __forceinline__ float sigf(float x){ return 1.0f/(1.0f+__expf(-x)); }
__device__ __forceinline__ float tanhf_(float x){ return 1.0f - 2.0f/(1.0f+__expf(2.0f*x)); }
__device__ __forceinline__ unsigned short f2bf(float x){
    union { float f; unsigned u; } v; v.f = x;
    return (unsigned short)((v.u + 0x8000u) >> 16);
}
// LDS-only barrier: do NOT drain vmcnt (global stores fly async past it)
__device__ __forceinline__ void bar_lds(){
    asm volatile("s_waitcnt lgkmcnt(0)\n\ts_barrier" ::: "memory");
}
__device__ __forceinline__ void wait_lds(){
    asm volatile("s_waitcnt lgkmcnt(0)" ::: "memory");
}
// native 2^x and 1/x
__device__ __forceinline__ float ex2(float x){ return __builtin_amdgcn_exp2f(x); }
__device__ __forceinline__ float rcp(float x){ return __builtin_amdgcn_rcpf(x); }

// ---------------------------------------------------------------------------
// Kernel 0: permuted xproj table, pre-scaled by log2(e).
// table[v][4*cell+gate] = LOG2E * (dot(W_ih1[gate*64+cell,:], emb[v,:]) + b_ih1 + b_hh1)
// ---------------------------------------------------------------------------
__global__ void k_table(const float* __restrict__ Wih, const float* __restrict__ emb,
                        const float* __restrict__ bih, const float* __restrict__ bhh,
                        float* __restrict__ table){
    const int p = threadIdx.x;
    const int v = blockIdx.x;
    const int orig = (p & 3) * H1 + (p >> 2);
    float s = bih[orig] + bhh[orig];
    if (v != 0){
        const float* w = Wih + orig * EMB;
        const float* e = emb + v * EMB;
        #pragma unroll 16
        for (int d = 0; d < EMB; ++d) s += w[d]*e[d];
    }
    table[v*256 + p] = s * LOG2E;
}

// ---------------------------------------------------------------------------
// Kernel 1: layer-1 LSTM. ONE WAVE PER BATCH ROW, 1024 blocks, no barriers.
// All 16 MFMA cols hold identical valid gates (B is h-broadcast). Producer
// lanes (col 0) write 16 cell-quads to wave-local LDS; lane l consumes cell
// l's (i,f,g,o) quad + its xproj quad. Weights pre-scaled by log2e.
// ---------------------------------------------------------------------------
__global__ __launch_bounds__(64, 1) void k_lstm1(
    const int* __restrict__ xidx, const float* __restrict__ Whh,
    const float* __restrict__ tbl_g, float* __restrict__ x2){
  __shared__ __align__(16) float table[VOCAB*256];     // 21504 B
  __shared__ __align__(16) f32x4 glds[64];             // 1024 B
  __shared__ __align__(16) unsigned short hlds[64];    // 128 B
  __shared__ int idxs[T1];                             // 2000 B

  const int l = threadIdx.x;
  const int row = blockIdx.x;
  const int kg = l >> 4;

  // one-time staging (single wave: wait_lds is enough, no barrier)
  { const f32x4* src = (const f32x4*)tbl_g;
    f32x4* dst = (f32x4*)table;
    #pragma unroll
    for (int i = 0; i < 21; ++i) dst[i*64 + l] = src[i*64 + l]; }
  for (int i = l; i < T1; i += 64) idxs[i] = xidx[row*T1 + i];
  hlds[l] = 0;

  // A fragments (permuted Whh * LOG2E), 16 tiles x K64
  bf16x8 af[16][2];
  #pragma unroll
  for (int tt = 0; tt < 16; ++tt){
      const int p = 16*tt + (l & 15);
      const int orig = (p & 3)*H1 + (p >> 2);
      #pragma unroll
      for (int c = 0; c < 2; ++c){
          const float* src = Whh + orig*H1 + c*32 + kg*8;
          bf16x8 f;
          #pragma unroll
          for (int j = 0; j < 8; ++j) f[j] = (short)f2bf(src[j] * LOG2E);
          af[tt][c] = f;
      }
  }

  char* hb = (char*)hlds;
  char* gb = (char*)glds;
  const bool prod = (l & 15) == 0;
  const float twoL = 2.0f * LOG2E;

  wait_lds();                       // idxs + hlds zeros visible to this wave

  int vcur = idxs[0];
  int vnext = idxs[1];
  float cc = 0.f, pm = -1e30f;
  int tm = 0, tp = 0;

  for (int t = 0; t < T1; ++t){
      // off-chain: this step's xproj quad for cell l
      f32x4 tvq = *(const f32x4*)&table[vcur*256 + 4*l];
      // B fragments: h broadcast (cells 8kg..8kg+7 | 32+8kg..+7)
      bf16x8 bf0 = *(const bf16x8*)(hb + 16*kg);
      bf16x8 bf1 = *(const bf16x8*)(hb + 64 + 16*kg);
      // idx lookahead (2 steps of slack)
      int vn2 = idxs[(t + 2 < T1) ? (t + 2) : 0];

      const f32x4 z4 = {0.f, 0.f, 0.f, 0.f};
      f32x4 acc[16];
      #pragma unroll
      for (int tt = 0; tt < 16; ++tt){
          f32x4 a = __builtin_amdgcn_mfma_f32_16x16x32_bf16(af[tt][0], bf0, z4, 0,0,0);
          acc[tt]  = __builtin_amdgcn_mfma_f32_16x16x32_bf16(af[tt][1], bf1, a, 0,0,0);
      }
      // redistribute: producer col writes cell-quad tt -> glds[4*tt+kg]
      if (prod){
          #pragma unroll
          for (int tt = 0; tt < 16; ++tt)
              *(f32x4*)(gb + 64*tt + 16*kg) = acc[tt];
      }
      vcur = vnext; vnext = vn2;
      wait_lds();
      f32x4 q = *(const f32x4*)(gb + 16*l);    // cell l: (i,f,g,o), pre-scaled
      float gi = q[0] + tvq[0];
      float gf = q[1] + tvq[1];
      float gg = q[2] + tvq[2];
      float go = q[3] + tvq[3];
      float si = rcp(1.f + ex2(-gi));
      float sf = rcp(1.f + ex2(-gf));
      float so = rcp(1.f + ex2(-go));
      float tg = 1.f - 2.f*rcp(1.f + ex2(gg + gg));
      cc = sf*cc + si*tg;
      float th = 1.f - 2.f*rcp(1.f + ex2(twoL*cc));
      float h = so*th;
      pm = fmaxf(pm, h);
      if (++tm == 5){
          x2[row*(TP*H1) + tp*H1 + l] = pm;    // async store, never drained
          pm = -1e30f; tm = 0; ++tp;
      }
      *(unsigned short*)(hb + 2*l) = f2bf(h);
      wait_lds();                   // order h-write before next step's reads
  }
}

// ---------------------------------------------------------------------------
// Kernel 2: layer-2 LSTM (unchanged from R5). 4 rows/block, 256 blocks,
// 8 waves; 26 gate tiles split 4,4,3,3,3,3,3,3; compress to 1 update/lane.
// ---------------------------------------------------------------------------
__global__ __launch_bounds__(512, 2) void k_lstm2(
    const float* __restrict__ x2, const float* __restrict__ Wih,
    const float* __restrict__ Whh, const float* __restrict__ bih,
    const float* __restrict__ bhh, const float* __restrict__ fcw,
    const float* __restrict__ fcb, float* __restrict__ out){
  __shared__ __align__(16) unsigned short blds[2][16*192];   // 12288 B
  __shared__ __align__(16) f32x4 gl2[8*64];                  // 8192 B
  __shared__ float fcred[8][4];

  const int tid = threadIdx.x;
  const int w = tid >> 6, l = tid & 63;
  const int b0 = blockIdx.x * 4;
  const int n = l & 15, kg = l >> 4;
  const int tlo = (w < 2) ? 4*w : 8 + 3*(w - 2);
  const int nt  = (w < 2) ? 4 : 3;

  { unsigned* bz0 = (unsigned*)blds;
    for (int i = tid; i < 3072; i += 512) bz0[i] = 0; }
  { float* gz = (float*)gl2;
    for (int i = tid; i < 2048; i += 512) gz[i] = 0.f; }

  bf16x8 af[4][6];
  #pragma unroll
  for (int u = 0; u < 4; ++u){
      if (u < nt){
          const int p = 16*(tlo + u) + n;
          const int cell_ = p >> 2, gate = p & 3;
          #pragma unroll
          for (int c = 0; c < 6; ++c){
              bf16x8 f;
              #pragma unroll
              for (int jj = 0; jj < 8; ++jj){
                  int k = c*32 + kg*8 + jj;
                  float vv = 0.f;
                  if (cell_ < H2){
                      if (k < 64)           vv = Wih[(gate*H2 + cell_)*H1 + k];
                      else if (k < 64 + H2) vv = Whh[(gate*H2 + cell_)*H2 + (k - 64)];
                  }
                  f[jj] = (short)f2bf(vv);
              }
              af[u][c] = f;
          }
      }
  }

  f32x4 bz[4];
  #pragma unroll
  for (int u = 0; u < 4; ++u){
      const int cu = 4*(tlo + u) + kg;
      f32x4 b = {0.f,0.f,0.f,0.f};
      if (u < nt && cu < H2){
          #pragma unroll
          for (int g = 0; g < 4; ++g) b[g] = bih[g*H2 + cu] + bhh[g*H2 + cu];
      }
      bz[u] = b;
  }

  const bool act = (l >> 2) < 4*nt;
  const int cellc = 4*tlo + (l >> 2);
  const int r_c = l & 3;
  float fwv = 0.f;
  if (act && cellc < H2) fwv = fcw[cellc];

  char* bb = (char*)blds;
  const int swz = (n & 7) << 4;
  int rb[6];
  #pragma unroll
  for (int c = 0; c < 6; ++c) rb[c] = (n*384 + 64*c + 16*kg) ^ swz;
  const int wbh = (r_c*384 + 2*(64 + cellc)) ^ (r_c << 4);

  const int xr = (tid >> 5) & 3, xc = tid & 31;
  const int xwb = (xr*384 + 4*xc) ^ (xr << 4);
  if (tid >= 384){
      float2 v = *(const float2*)&x2[(b0 + xr)*(TP*H1) + 2*xc];
      unsigned pk = (unsigned)f2bf(v.x) | ((unsigned)f2bf(v.y) << 16);
      *(unsigned*)(bb + xwb) = pk;
  }
  float cc = 0.f, hv = 0.f;
  __syncthreads();

  int rp = 0;
  for (int t = 0; t < TP; ++t){
      float2 xn = {0.f, 0.f};
      if (tid >= 384 && t + 1 < TP)
          xn = *(const float2*)&x2[(b0 + xr)*(TP*H1) + (t+1)*H1 + 2*xc];
      bf16x8 bf[6];
      #pragma unroll
      for (int c = 0; c < 6; ++c) bf[c] = *(const bf16x8*)(bb + rp + rb[c]);
      #pragma unroll
      for (int u = 0; u < 4; ++u){
          if (u < nt){
              f32x4 z = bz[u];
              #pragma unroll
              for (int c = 0; c < 6; ++c)
                  z = __builtin_amdgcn_mfma_f32_16x16x32_bf16(af[u][c], bf[c], z, 0,0,0);
              if (n < 4) gl2[w*64 + kg*4 + n + 16*u] = z;
          }
      }
      wait_lds();
      f32x4 g = gl2[w*64 + l];
      cc = sigf(g[1])*cc + sigf(g[0])*tanhf_(g[2]);
      hv = sigf(g[3])*tanhf_(cc);
      const int wp = rp ^ 6144;
      if (act) *(unsigned short*)(bb + wp + wbh) = f2bf(hv);
      if (tid >= 384 && t + 1 < TP){
          unsigned pk = (unsigned)f2bf(xn.x) | ((unsigned)f2bf(xn.y) << 16);
          *(unsigned*)(bb + wp + xwb) = pk;
      }
      rp = wp;
      bar_lds();
  }

  float p = hv * fwv;
  p += __shfl_xor(p, 4);
  p += __shfl_xor(p, 8);
  p += __shfl_xor(p, 16);
  p += __shfl_xor(p, 32);
  if (l < 4) fcred[w][l] = p;
  __syncthreads();
  if (tid < 4){
      float s = 0.f;
      #pragma unroll
      for (int ww = 0; ww < 8; ++ww) s += fcred[ww][tid];
      out[b0 + tid] = sigf(s + fcb[0]);
  }
}

// ---------------------------------------------------------------------------
extern "C" void kernel_launch(void* const* d_in, const int* in_sizes, int n_in,
                              void* d_out, int out_size, void* d_ws, size_t ws_size,
                              hipStream_t stream) {
    const int*   x_idx = (const int*)  d_in[0];
    const float* emb   = (const float*)d_in[1];
    const float* Wih1  = (const float*)d_in[2];
    const float* Whh1  = (const float*)d_in[3];
    const float* bih1  = (const float*)d_in[4];
    const float* bhh1  = (const float*)d_in[5];
    const float* Wih2  = (const float*)d_in[6];
    const float* Whh2  = (const float*)d_in[7];
    const float* bih2  = (const float*)d_in[8];
    const float* bhh2  = (const float*)d_in[9];
    const float* fcw   = (const float*)d_in[10];
    const float* fcb   = (const float*)d_in[11];
    float* out = (float*)d_out;

    float* table = (float*)d_ws;                       // 21*256*4 = 21504 B
    float* x2    = (float*)((char*)d_ws + 32768);      // 1024*100*64*4 = 26.2 MB

    k_table<<<VOCAB, 256, 0, stream>>>(Wih1, emb, bih1, bhh1, table);
    k_lstm1<<<NB, 64, 0, stream>>>(x_idx, Whh1, table, x2);
    k_lstm2<<<NB / 4, 512, 0, stream>>>(x2, Wih2, Whh2, bih2, bhh2, fcw, fcb, out);
}

// Round 7
// 319.453 us; speedup vs baseline: 1.6703x; 1.6703x over previous
//
#include <hip/hip_runtime.h>

#define VOCAB 21
#define EMB 128
#define H1 64
#define H2 100
#define T1 500
#define TP 100
#define NB 1024
#define LOG2E 1.44269504f

typedef __attribute__((ext_vector_type(8))) short bf16x8;
typedef __attribute__((ext_vector_type(4))) float f32x4;

__device__ __forceinline__ unsigned short f2bf(float x){
    union { float f; unsigned u; } v; v.f = x;
    return (unsigned short)((v.u + 0x8000u) >> 16);
}
// LDS-only barrier: do NOT drain vmcnt (global stores fly async past it)
__device__ __forceinline__ void bar_lds(){
    asm volatile("s_waitcnt lgkmcnt(0)\n\ts_barrier" ::: "memory");
}
__device__ __forceinline__ void wait_lds(){
    asm volatile("s_waitcnt lgkmcnt(0)" ::: "memory");
}
__device__ __forceinline__ float ex2(float x){ return __builtin_amdgcn_exp2f(x); }
__device__ __forceinline__ float rcp(float x){ return __builtin_amdgcn_rcpf(x); }

// ---------------------------------------------------------------------------
// Kernel 0: permuted xproj table, pre-scaled by log2(e).
// table[v][4*cell+gate] = LOG2E*(dot(W_ih1[gate*64+cell,:], emb[v,:]) + b_ih1 + b_hh1)
// ---------------------------------------------------------------------------
__global__ void k_table(const float* __restrict__ Wih, const float* __restrict__ emb,
                        const float* __restrict__ bih, const float* __restrict__ bhh,
                        float* __restrict__ table){
    const int p = threadIdx.x;
    const int v = blockIdx.x;
    const int orig = (p & 3) * H1 + (p >> 2);
    float s = bih[orig] + bhh[orig];
    if (v != 0){
        const float* w = Wih + orig * EMB;
        const float* e = emb + v * EMB;
        #pragma unroll 16
        for (int d = 0; d < EMB; ++d) s += w[d]*e[d];
    }
    table[v*256 + p] = s * LOG2E;
}

// ---------------------------------------------------------------------------
// Kernel 1: layer-1 LSTM. 4 rows/block, 256 blocks, 4 waves.
// Wave w owns gate tiles 4w..4w+3 == cells 16w..16w+15 (all gates, all rows):
// producer lanes (col<4) write quads to WAVE-PRIVATE glds[cell][row]; the 64
// consumer lanes (16 cells x 4 rows) each do exactly ONE real update.
// One lgkm-barrier per step. xproj = consumer-side table quad, prefetched.
// ---------------------------------------------------------------------------
__global__ __launch_bounds__(256, 1) void k_lstm1(
    const int* __restrict__ xidx, const float* __restrict__ Whh,
    const float* __restrict__ tbl_g, float* __restrict__ x2){
  __shared__ __align__(16) float table[VOCAB*256];       // 21504 B
  __shared__ __align__(16) unsigned short hbuf[2][16*64];// 4096 B (XOR-swizzled)
  __shared__ __align__(16) f32x4 glds[4*16*4];           // 4096 B [wave][cell16][row4]
  __shared__ int idxs[4*T1];                             // 8000 B

  const int tid = threadIdx.x;
  const int w = tid >> 6, l = tid & 63;
  const int b0 = blockIdx.x * 4;
  const int n = l & 15, kg = l >> 4;       // producer coords: col n, k-group kg

  for (int i = tid; i < VOCAB*256; i += 256) table[i] = tbl_g[i];
  for (int i = tid; i < 4*T1; i += 256){
      int r = i / T1, t = i - r*T1;
      idxs[i] = xidx[(b0 + r)*T1 + t];
  }
  { unsigned short* hz = (unsigned short*)hbuf;
    for (int i = tid; i < 2048; i += 256) hz[i] = 0; }

  // A fragments (permuted Whh * LOG2E): tiles gt=4w+u
  bf16x8 af[4][2];
  #pragma unroll
  for (int u = 0; u < 4; ++u){
      const int p = 16*(4*w + u) + n;
      const int orig = (p & 3)*H1 + (p >> 2);
      #pragma unroll
      for (int c = 0; c < 2; ++c){
          const float* src = Whh + orig*H1 + c*32 + kg*8;
          bf16x8 f;
          #pragma unroll
          for (int j = 0; j < 8; ++j) f[j] = (short)f2bf(src[j] * LOG2E);
          af[u][c] = f;
      }
  }

  char* hb = (char*)hbuf;
  char* gb = (char*)glds + 1024*w;
  const int swz = (n & 7) << 4;
  const int rb0 = (n*128 + 16*kg) ^ swz;
  const int rb1 = (n*128 + 64 + 16*kg) ^ swz;
  // consumer: lane l -> cell = 16w + (l>>2), row r_c = l&3
  const int cell = 16*w + (l >> 2);
  const int r_c  = l & 3;
  const int wbh  = (r_c*128 + 2*cell) ^ (r_c << 4);
  const float twoL = 2.0f * LOG2E;

  float cc = 0.f, pm = -1e30f;
  __syncthreads();

  int vnext = idxs[r_c*T1];                    // v for t=0
  f32x4 tvq = *(const f32x4*)&table[vnext*256 + 4*cell];
  vnext = idxs[r_c*T1 + 1];
  const f32x4 z4 = {0.f, 0.f, 0.f, 0.f};

  int rp = 0, tm = 0, tp = 0;
  for (int t = 0; t < T1; ++t){
      bf16x8 bf0 = *(const bf16x8*)(hb + rp + rb0);
      bf16x8 bf1 = *(const bf16x8*)(hb + rp + rb1);
      #pragma unroll
      for (int u = 0; u < 4; ++u){
          f32x4 a = __builtin_amdgcn_mfma_f32_16x16x32_bf16(af[u][0], bf0, z4, 0,0,0);
          a        = __builtin_amdgcn_mfma_f32_16x16x32_bf16(af[u][1], bf1, a, 0,0,0);
          if (n < 4)                            // cell 16w+4u+kg, row n
              *(f32x4*)(gb + 256*u + 64*kg + 16*n) = a;
      }
      wait_lds();
      f32x4 q = *(const f32x4*)(gb + 16*l);    // (i,f,g,o) of (cell, r_c)
      // off-chain prefetches for t+1 (complete during activation)
      f32x4 tvn = *(const f32x4*)&table[vnext*256 + 4*cell];
      int vn2 = idxs[r_c*T1 + ((t + 2 < T1) ? (t + 2) : 0)];
      float gi = q[0] + tvq[0];
      float gf = q[1] + tvq[1];
      float gg = q[2] + tvq[2];
      float go = q[3] + tvq[3];
      float si = rcp(1.f + ex2(-gi));
      float sf = rcp(1.f + ex2(-gf));
      float so = rcp(1.f + ex2(-go));
      float tg = 1.f - 2.f*rcp(1.f + ex2(gg + gg));
      cc = sf*cc + si*tg;
      float th = 1.f - 2.f*rcp(1.f + ex2(twoL*cc));
      float h = so*th;
      const int wp = rp ^ 2048;
      *(unsigned short*)(hb + wp + wbh) = f2bf(h);
      pm = fmaxf(pm, h);
      if (++tm == 5){
          x2[(b0 + r_c)*(TP*H1) + tp*H1 + cell] = pm;   // async, never drained
          pm = -1e30f; tm = 0; ++tp;
      }
      tvq = tvn; vnext = vn2;
      rp = wp;
      bar_lds();
  }
}

// ---------------------------------------------------------------------------
// Kernel 2: layer-2 LSTM. 4 rows/block, 256 blocks, 8 waves; 26 tiles split
// 4,4,3,3,3,3,3,3. Wave-local redistribute into gl2[cell][row]; <=1 real
// update/lane. Split accumulators halve the K=192 MFMA chain. log2e folded.
// ---------------------------------------------------------------------------
__global__ __launch_bounds__(512, 1) void k_lstm2(
    const float* __restrict__ x2, const float* __restrict__ Wih,
    const float* __restrict__ Whh, const float* __restrict__ bih,
    const float* __restrict__ bhh, const float* __restrict__ fcw,
    const float* __restrict__ fcb, float* __restrict__ out){
  __shared__ __align__(16) unsigned short blds[2][16*192];   // 12288 B
  __shared__ __align__(16) f32x4 gl2[108*4];                 // 6912 B [cell][row]
  __shared__ float fcred[8][4];

  const int tid = threadIdx.x;
  const int w = tid >> 6, l = tid & 63;
  const int b0 = blockIdx.x * 4;
  const int n = l & 15, kg = l >> 4;
  const int tlo = (w < 2) ? 4*w : 8 + 3*(w - 2);
  const int nt  = (w < 2) ? 4 : 3;

  { unsigned* bz0 = (unsigned*)blds;
    for (int i = tid; i < 3072; i += 512) bz0[i] = 0; }
  { float* gz = (float*)gl2;
    for (int i = tid; i < 432*4; i += 512) gz[i] = 0.f; }

  // A fragments: [W_ih2 | W_hh2] permuted * LOG2E, zero-padded
  bf16x8 af[4][6];
  #pragma unroll
  for (int u = 0; u < 4; ++u){
      if (u < nt){
          const int p = 16*(tlo + u) + n;
          const int cell_ = p >> 2, gate = p & 3;
          #pragma unroll
          for (int c = 0; c < 6; ++c){
              bf16x8 f;
              #pragma unroll
              for (int jj = 0; jj < 8; ++jj){
                  int k = c*32 + kg*8 + jj;
                  float vv = 0.f;
                  if (cell_ < H2){
                      if (k < 64)           vv = Wih[(gate*H2 + cell_)*H1 + k];
                      else if (k < 64 + H2) vv = Whh[(gate*H2 + cell_)*H2 + (k - 64)];
                  }
                  f[jj] = (short)f2bf(vv * LOG2E);
              }
              af[u][c] = f;
          }
      }
  }

  // bias C-init quads (producer layout), * LOG2E
  f32x4 bz[4];
  #pragma unroll
  for (int u = 0; u < 4; ++u){
      const int cu = 4*(tlo + u) + kg;
      f32x4 b = {0.f,0.f,0.f,0.f};
      if (u < nt && cu < H2){
          #pragma unroll
          for (int g = 0; g < 4; ++g) b[g] = (bih[g*H2 + cu] + bhh[g*H2 + cu]) * LOG2E;
      }
      bz[u] = b;
  }

  // consumer: lane l -> cell = 4*tlo + (l>>2), row = l&3; active if in-range
  const bool act = (l >> 2) < 4*nt;
  const int cellc = 4*tlo + (l >> 2);
  const int r_c = l & 3;
  const float fwv = (act && cellc < H2) ? fcw[cellc] : 0.f;
  const float twoL = 2.0f * LOG2E;

  char* bb = (char*)blds;
  char* gb = (char*)gl2;
  const int swz = (n & 7) << 4;
  int rb[6];
  #pragma unroll
  for (int c = 0; c < 6; ++c) rb[c] = (n*384 + 64*c + 16*kg) ^ swz;
  const int wbh = (r_c*384 + 2*(64 + cellc)) ^ (r_c << 4);

  // x-staging role: waves 6,7 (tid>=384): row xr, cells 2*xc, 2*xc+1
  const int xr = (tid >> 5) & 3, xc = tid & 31;
  const int xwb = (xr*384 + 4*xc) ^ (xr << 4);
  if (tid >= 384){
      float2 v = *(const float2*)&x2[(b0 + xr)*(TP*H1) + 2*xc];
      unsigned pk = (unsigned)f2bf(v.x) | ((unsigned)f2bf(v.y) << 16);
      *(unsigned*)(bb + xwb) = pk;
  }
  float cc = 0.f, hv = 0.f;
  __syncthreads();

  int rp = 0;
  for (int t = 0; t < TP; ++t){
      float2 xn = {0.f, 0.f};
      if (tid >= 384 && t + 1 < TP)              // T14 issue-early
          xn = *(const float2*)&x2[(b0 + xr)*(TP*H1) + (t+1)*H1 + 2*xc];
      bf16x8 bf[6];
      #pragma unroll
      for (int c = 0; c < 6; ++c) bf[c] = *(const bf16x8*)(bb + rp + rb[c]);
      #pragma unroll
      for (int u = 0; u < 4; ++u){
          if (u < nt){
              f32x4 za = __builtin_amdgcn_mfma_f32_16x16x32_bf16(af[u][0], bf[0], bz[u], 0,0,0);
              f32x4 zb = __builtin_amdgcn_mfma_f32_16x16x32_bf16(af[u][1], bf[1], (f32x4){0.f,0.f,0.f,0.f}, 0,0,0);
              za = __builtin_amdgcn_mfma_f32_16x16x32_bf16(af[u][2], bf[2], za, 0,0,0);
              zb = __builtin_amdgcn_mfma_f32_16x16x32_bf16(af[u][3], bf[3], zb, 0,0,0);
              za = __builtin_amdgcn_mfma_f32_16x16x32_bf16(af[u][4], bf[4], za, 0,0,0);
              zb = __builtin_amdgcn_mfma_f32_16x16x32_bf16(af[u][5], bf[5], zb, 0,0,0);
              f32x4 z = za + zb;
              if (n < 4)                          // cell 4*(tlo+u)+kg, row n
                  *(f32x4*)(gb + 256*(tlo + u) + 64*kg + 16*n) = z;
          }
      }
      wait_lds();
      const int wp = rp ^ 6144;
      if (act){
          f32x4 q = *(const f32x4*)(gb + 256*tlo + 16*l);
          float si = rcp(1.f + ex2(-q[0]));
          float sf = rcp(1.f + ex2(-q[1]));
          float so = rcp(1.f + ex2(-q[3]));
          float tg = 1.f - 2.f*rcp(1.f + ex2(q[2] + q[2]));
          cc = sf*cc + si*tg;
          float th = 1.f - 2.f*rcp(1.f + ex2(twoL*cc));
          hv = so*th;
          *(unsigned short*)(bb + wp + wbh) = f2bf(hv);
      }
      if (tid >= 384 && t + 1 < TP){             // write-late
          unsigned pk = (unsigned)f2bf(xn.x) | ((unsigned)f2bf(xn.y) << 16);
          *(unsigned*)(bb + wp + xwb) = pk;
      }
      rp = wp;
      bar_lds();
  }

  // FC + sigmoid: p=0 on junk lanes (NaN-proof), reduce cells then waves
  float p = (act && cellc < H2) ? hv * fwv : 0.f;
  p += __shfl_xor(p, 4);
  p += __shfl_xor(p, 8);
  p += __shfl_xor(p, 16);
  p += __shfl_xor(p, 32);
  if (l < 4) fcred[w][l] = p;
  __syncthreads();
  if (tid < 4){
      float s = 0.f;
      #pragma unroll
      for (int ww = 0; ww < 8; ++ww) s += fcred[ww][tid];
      s += fcb[0];
      out[b0 + tid] = rcp(1.f + ex2(-s * LOG2E));
  }
}

// ---------------------------------------------------------------------------
extern "C" void kernel_launch(void* const* d_in, const int* in_sizes, int n_in,
                              void* d_out, int out_size, void* d_ws, size_t ws_size,
                              hipStream_t stream) {
    const int*   x_idx = (const int*)  d_in[0];
    const float* emb   = (const float*)d_in[1];
    const float* Wih1  = (const float*)d_in[2];
    const float* Whh1  = (const float*)d_in[3];
    const float* bih1  = (const float*)d_in[4];
    const float* bhh1  = (const float*)d_in[5];
    const float* Wih2  = (const float*)d_in[6];
    const float* Whh2  = (const float*)d_in[7];
    const float* bih2  = (const float*)d_in[8];
    const float* bhh2  = (const float*)d_in[9];
    const float* fcw   = (const float*)d_in[10];
    const float* fcb   = (const float*)d_in[11];
    float* out = (float*)d_out;

    float* table = (float*)d_ws;                       // 21*256*4 = 21504 B
    float* x2    = (float*)((char*)d_ws + 32768);      // 1024*100*64*4 = 26.2 MB

    k_table<<<VOCAB, 256, 0, stream>>>(Wih1, emb, bih1, bhh1, table);
    k_lstm1<<<NB / 4, 256, 0, stream>>>(x_idx, Whh1, table, x2);
    k_lstm2<<<NB / 4, 512, 0, stream>>>(x2, Wih2, Whh2, bih2, bhh2, fcw, fcb, out);
}